// Round 8
// baseline (504.506 us; speedup 1.0000x reference)
//
#include <hip/hip_runtime.h>
#include <limits.h>
#include <cstdint>

typedef __bf16 bf16_t;
typedef __attribute__((ext_vector_type(8))) __bf16 bf16x8;
typedef __attribute__((ext_vector_type(4))) float f32x4;

#define CH 64     // edges per wave in edge_stream
#define RING 16   // outstanding Y gathers per wave

// ---------------------------------------------------------------------------
__global__ void convert_bf16_kernel(const float* __restrict__ in,
                                    bf16_t* __restrict__ out, int n) {
  int i = (blockIdx.x * blockDim.x + threadIdx.x) * 4;
  if (i < n) {
    float4 v = *reinterpret_cast<const float4*>(in + i);
    bf16_t o0 = (bf16_t)v.x, o1 = (bf16_t)v.y, o2 = (bf16_t)v.z, o3 = (bf16_t)v.w;
    ushort4 u;
    u.x = __builtin_bit_cast(unsigned short, o0);
    u.y = __builtin_bit_cast(unsigned short, o1);
    u.z = __builtin_bit_cast(unsigned short, o2);
    u.w = __builtin_bit_cast(unsigned short, o3);
    *reinterpret_cast<ushort4*>(out + i) = u;
  }
}

// ---------------------------------------------------------------------------
// Pack W (KROWS x 128 fp32) -> MFMA B-frag order, bf16, K padded to KTILES*32.
// ---------------------------------------------------------------------------
__global__ void pack_w_kernel(const float* __restrict__ W,
                              bf16_t* __restrict__ packed, int KROWS, int KTILES) {
  int idx = blockIdx.x * blockDim.x + threadIdx.x;
  if (idx >= KTILES * 8 * 64 * 8) return;
  int j  = idx & 7;
  int L  = (idx >> 3) & 63;
  int nt = (idx >> 9) & 7;
  int kt = idx >> 12;
  int k = kt * 32 + (L >> 4) * 8 + j;
  int n = nt * 16 + (L & 15);
  float v = (k < KROWS) ? W[(size_t)k * 128 + n] : 0.f;
  packed[idx] = (bf16_t)v;
}

// ---------------------------------------------------------------------------
// Y = Xbf @ Wtop (N x 128, K=128) via bf16 MFMA, bf16 output.
// Also zeroes the pooled buffer for this WG's rows (fuses zero_kernel).
// ---------------------------------------------------------------------------
__global__ __launch_bounds__(256, 4) void yproj_mfma(
    const bf16_t* __restrict__ Xbf, const bf16_t* __restrict__ Wtpk,
    bf16_t* __restrict__ Ybf, float* __restrict__ pooled, int N)
{
  const int tid = threadIdx.x;
  const int base = blockIdx.x * 128;

  float4 z = make_float4(0.f, 0.f, 0.f, 0.f);
  #pragma unroll
  for (int i = 0; i < 16; ++i) {
    int idx = tid + i * 256;
    int row = base + (idx >> 5);
    if (row < N)
      reinterpret_cast<float4*>(pooled)[(size_t)row * 32 + (idx & 31)] = z;
  }

  const int lane = tid & 63;
  const int w    = tid >> 6;
  const int q    = lane >> 4;
  const int ln   = lane & 15;
  const int n0   = base + w * 32;

  int r0 = n0 + ln, r1 = n0 + 16 + ln;
  int r0c = (r0 < N) ? r0 : (N - 1);
  int r1c = (r1 < N) ? r1 : (N - 1);
  const bf16_t* x0 = Xbf + (size_t)r0c * 128 + q * 8;
  const bf16_t* x1 = Xbf + (size_t)r1c * 128 + q * 8;

  f32x4 acc[2][8];
  #pragma unroll
  for (int mt = 0; mt < 2; ++mt)
    #pragma unroll
    for (int nt = 0; nt < 8; ++nt)
      #pragma unroll
      for (int r = 0; r < 4; ++r) acc[mt][nt][r] = 0.f;

  const bf16x8* Wp = reinterpret_cast<const bf16x8*>(Wtpk);
  #pragma unroll
  for (int kt = 0; kt < 4; ++kt) {
    bf16x8 a0 = *reinterpret_cast<const bf16x8*>(x0 + kt * 32);
    bf16x8 a1 = *reinterpret_cast<const bf16x8*>(x1 + kt * 32);
    #pragma unroll
    for (int nt = 0; nt < 8; ++nt) {
      bf16x8 bfrag = Wp[(kt * 8 + nt) * 64 + lane];
      acc[0][nt] = __builtin_amdgcn_mfma_f32_16x16x32_bf16(a0, bfrag, acc[0][nt], 0, 0, 0);
      acc[1][nt] = __builtin_amdgcn_mfma_f32_16x16x32_bf16(a1, bfrag, acc[1][nt], 0, 0, 0);
    }
  }

  #pragma unroll
  for (int mt = 0; mt < 2; ++mt) {
    #pragma unroll
    for (int r = 0; r < 4; ++r) {
      int row = n0 + mt * 16 + q * 4 + r;
      if (row < N) {
        #pragma unroll
        for (int nt = 0; nt < 8; ++nt) {
          int col = nt * 16 + ln;
          Ybf[(size_t)row * 128 + col] = (bf16_t)acc[mt][nt][r];
        }
      }
    }
  }
}

// ---------------------------------------------------------------------------
// Edge pass, streaming, scalarized metadata + 16-deep gather ring.
// h[e][c] = ReLU(Y[nbr[e]][c] + bb[c] + a_e . Wbot[:,c]); pooled = seg-max.
// ReLU folded into the running max (v init 0). Ring slot i&15 is consumed
// then immediately reloaded for edge i+16 -> no ring copies, ~16 loads in
// flight per wave. All control flow wave-uniform.
// ---------------------------------------------------------------------------
__global__ __launch_bounds__(256) void edge_stream(
    const bf16_t* __restrict__ Y,        // N x 128 bf16
    const float* __restrict__ Wb,        // 132 x 128; rows 128..131 = Wbot
    const float* __restrict__ bb,        // 128
    const float* __restrict__ add_info,  // E x 4
    const int* __restrict__ nbr, const int* __restrict__ segs,
    float* __restrict__ pooled, int E)
{
  const int lane = threadIdx.x & 63;
  const int wv = __builtin_amdgcn_readfirstlane(threadIdx.x >> 6);  // SGPR
  const int e0 = (blockIdx.x * 4 + wv) * CH;                        // uniform
  if (e0 >= E) return;
  const int c0 = lane * 2;

  float wka[4], wkb[4];
  #pragma unroll
  for (int k = 0; k < 4; ++k) {
    wka[k] = Wb[(size_t)(128 + k) * 128 + c0];
    wkb[k] = Wb[(size_t)(128 + k) * 128 + c0 + 1];
  }
  const float bb0 = bb[c0], bb1 = bb[c0 + 1];

  unsigned* pooled_u = reinterpret_cast<unsigned*>(pooled);
  float v0 = 0.f, v1 = 0.f;
  int cur = segs[e0];                                               // scalar

  if (e0 + CH <= E) {
    // ---- hot path: tail-free, fully uniform control flow ----
    unsigned ybuf[RING];
    #pragma unroll
    for (int j = 0; j < RING; ++j)
      ybuf[j] = *reinterpret_cast<const unsigned*>(
          Y + (size_t)nbr[e0 + j] * 128 + c0);

    #pragma unroll
    for (int i = 0; i < CH; ++i) {
      const int e = e0 + i;                                         // uniform
      int sg = segs[e];                                             // scalar
      if (sg != cur) {                                              // uniform branch
        if (v0 > 0.f) atomicMax(&pooled_u[(size_t)cur * 128 + c0], __float_as_uint(v0));
        if (v1 > 0.f) atomicMax(&pooled_u[(size_t)cur * 128 + c0 + 1], __float_as_uint(v1));
        v0 = 0.f; v1 = 0.f; cur = sg;
      }
      unsigned yb = ybuf[i & (RING - 1)];
      if (i + RING < CH)
        ybuf[i & (RING - 1)] = *reinterpret_cast<const unsigned*>(
            Y + (size_t)nbr[e0 + i + RING] * 128 + c0);
      float y0 = __uint_as_float(yb << 16);
      float y1 = __uint_as_float(yb & 0xffff0000u);
      const float* ai = add_info + (size_t)e * 4;                   // scalar x4
      float a0 = ai[0], a1 = ai[1], a2 = ai[2], a3 = ai[3];
      float t0 = y0 + bb0 + a0 * wka[0] + a1 * wka[1] + a2 * wka[2] + a3 * wka[3];
      float t1 = y1 + bb1 + a0 * wkb[0] + a1 * wkb[1] + a2 * wkb[2] + a3 * wkb[3];
      v0 = fmaxf(v0, t0);   // ReLU folded: v init 0 -> v = relu(max(t))
      v1 = fmaxf(v1, t1);
    }
  } else {
    // ---- tail path (generic, still uniform control flow) ----
    const int rem = E - e0;
    for (int i = 0; i < rem; ++i) {
      const int e = e0 + i;
      int sg = segs[e];
      if (sg != cur) {
        if (v0 > 0.f) atomicMax(&pooled_u[(size_t)cur * 128 + c0], __float_as_uint(v0));
        if (v1 > 0.f) atomicMax(&pooled_u[(size_t)cur * 128 + c0 + 1], __float_as_uint(v1));
        v0 = 0.f; v1 = 0.f; cur = sg;
      }
      unsigned yb = *reinterpret_cast<const unsigned*>(
          Y + (size_t)nbr[e] * 128 + c0);
      float y0 = __uint_as_float(yb << 16);
      float y1 = __uint_as_float(yb & 0xffff0000u);
      const float* ai = add_info + (size_t)e * 4;
      float a0 = ai[0], a1 = ai[1], a2 = ai[2], a3 = ai[3];
      float t0 = y0 + bb0 + a0 * wka[0] + a1 * wka[1] + a2 * wka[2] + a3 * wka[3];
      float t1 = y1 + bb1 + a0 * wkb[0] + a1 * wkb[1] + a2 * wkb[2] + a3 * wkb[3];
      v0 = fmaxf(v0, t0);
      v1 = fmaxf(v1, t1);
    }
  }
  if (v0 > 0.f) atomicMax(&pooled_u[(size_t)cur * 128 + c0], __float_as_uint(v0));
  if (v1 > 0.f) atomicMax(&pooled_u[(size_t)cur * 128 + c0 + 1], __float_as_uint(v1));
}

// ---------------------------------------------------------------------------
// featsOut = featsIn + pooled @ Wo + bo via bf16 MFMA; emits bf16 copy.
// ---------------------------------------------------------------------------
__global__ __launch_bounds__(256, 4) void update_mfma(
    const float* __restrict__ featsIn, const float* __restrict__ pooled,
    const bf16_t* __restrict__ Wopk, const float* __restrict__ bo,
    float* __restrict__ featsOut, bf16_t* __restrict__ featsOutBf, int N)
{
  const int tid  = threadIdx.x;
  const int lane = tid & 63;
  const int w    = tid >> 6;
  const int q    = lane >> 4;
  const int ln   = lane & 15;
  const int n0   = blockIdx.x * 128 + w * 32;

  int r0 = n0 + ln, r1 = n0 + 16 + ln;
  int r0c = (r0 < N) ? r0 : (N - 1);
  int r1c = (r1 < N) ? r1 : (N - 1);
  const float* p0 = pooled + (size_t)r0c * 128 + q * 8;
  const float* p1 = pooled + (size_t)r1c * 128 + q * 8;

  f32x4 acc[2][8];
  #pragma unroll
  for (int mt = 0; mt < 2; ++mt)
    #pragma unroll
    for (int nt = 0; nt < 8; ++nt)
      #pragma unroll
      for (int r = 0; r < 4; ++r) acc[mt][nt][r] = 0.f;

  const bf16x8* Wp = reinterpret_cast<const bf16x8*>(Wopk);
  #pragma unroll
  for (int kt = 0; kt < 4; ++kt) {
    float4 f0a = *reinterpret_cast<const float4*>(p0 + kt * 32);
    float4 f0b = *reinterpret_cast<const float4*>(p0 + kt * 32 + 4);
    float4 f1a = *reinterpret_cast<const float4*>(p1 + kt * 32);
    float4 f1b = *reinterpret_cast<const float4*>(p1 + kt * 32 + 4);
    bf16x8 a0, a1;
    a0[0] = (bf16_t)f0a.x; a0[1] = (bf16_t)f0a.y; a0[2] = (bf16_t)f0a.z; a0[3] = (bf16_t)f0a.w;
    a0[4] = (bf16_t)f0b.x; a0[5] = (bf16_t)f0b.y; a0[6] = (bf16_t)f0b.z; a0[7] = (bf16_t)f0b.w;
    a1[0] = (bf16_t)f1a.x; a1[1] = (bf16_t)f1a.y; a1[2] = (bf16_t)f1a.z; a1[3] = (bf16_t)f1a.w;
    a1[4] = (bf16_t)f1b.x; a1[5] = (bf16_t)f1b.y; a1[6] = (bf16_t)f1b.z; a1[7] = (bf16_t)f1b.w;
    #pragma unroll
    for (int nt = 0; nt < 8; ++nt) {
      bf16x8 bfrag = Wp[(kt * 8 + nt) * 64 + lane];
      acc[0][nt] = __builtin_amdgcn_mfma_f32_16x16x32_bf16(a0, bfrag, acc[0][nt], 0, 0, 0);
      acc[1][nt] = __builtin_amdgcn_mfma_f32_16x16x32_bf16(a1, bfrag, acc[1][nt], 0, 0, 0);
    }
  }

  float bov[8];
  #pragma unroll
  for (int nt = 0; nt < 8; ++nt) bov[nt] = bo[nt * 16 + ln];

  #pragma unroll
  for (int mt = 0; mt < 2; ++mt) {
    #pragma unroll
    for (int r = 0; r < 4; ++r) {
      int row = n0 + mt * 16 + q * 4 + r;
      if (row < N) {
        #pragma unroll
        for (int nt = 0; nt < 8; ++nt) {
          int col = nt * 16 + ln;
          float o = featsIn[(size_t)row * 128 + col] + acc[mt][nt][r] + bov[nt];
          featsOut[(size_t)row * 128 + col] = o;
          featsOutBf[(size_t)row * 128 + col] = (bf16_t)o;
        }
      }
    }
  }
}

// ---------------------------------------------------------------------------
// Block-1 update FUSED with final projection:
// out[n] = (featsIn[n] + pooled[n] @ Wo + bo) . Wf + bf
// ---------------------------------------------------------------------------
__global__ __launch_bounds__(256, 4) void update_final_mfma(
    const float* __restrict__ featsIn, const float* __restrict__ pooled,
    const bf16_t* __restrict__ Wopk, const float* __restrict__ bo,
    const float* __restrict__ Wf, const float* __restrict__ bf_,
    float* __restrict__ out, int N)
{
  const int tid  = threadIdx.x;
  const int lane = tid & 63;
  const int w    = tid >> 6;
  const int q    = lane >> 4;
  const int ln   = lane & 15;
  const int n0   = blockIdx.x * 128 + w * 32;

  int r0 = n0 + ln, r1 = n0 + 16 + ln;
  int r0c = (r0 < N) ? r0 : (N - 1);
  int r1c = (r1 < N) ? r1 : (N - 1);
  const float* p0 = pooled + (size_t)r0c * 128 + q * 8;
  const float* p1 = pooled + (size_t)r1c * 128 + q * 8;

  f32x4 acc[2][8];
  #pragma unroll
  for (int mt = 0; mt < 2; ++mt)
    #pragma unroll
    for (int nt = 0; nt < 8; ++nt)
      #pragma unroll
      for (int r = 0; r < 4; ++r) acc[mt][nt][r] = 0.f;

  const bf16x8* Wp = reinterpret_cast<const bf16x8*>(Wopk);
  #pragma unroll
  for (int kt = 0; kt < 4; ++kt) {
    float4 f0a = *reinterpret_cast<const float4*>(p0 + kt * 32);
    float4 f0b = *reinterpret_cast<const float4*>(p0 + kt * 32 + 4);
    float4 f1a = *reinterpret_cast<const float4*>(p1 + kt * 32);
    float4 f1b = *reinterpret_cast<const float4*>(p1 + kt * 32 + 4);
    bf16x8 a0, a1;
    a0[0] = (bf16_t)f0a.x; a0[1] = (bf16_t)f0a.y; a0[2] = (bf16_t)f0a.z; a0[3] = (bf16_t)f0a.w;
    a0[4] = (bf16_t)f0b.x; a0[5] = (bf16_t)f0b.y; a0[6] = (bf16_t)f0b.z; a0[7] = (bf16_t)f0b.w;
    a1[0] = (bf16_t)f1a.x; a1[1] = (bf16_t)f1a.y; a1[2] = (bf16_t)f1a.z; a1[3] = (bf16_t)f1a.w;
    a1[4] = (bf16_t)f1b.x; a1[5] = (bf16_t)f1b.y; a1[6] = (bf16_t)f1b.z; a1[7] = (bf16_t)f1b.w;
    #pragma unroll
    for (int nt = 0; nt < 8; ++nt) {
      bf16x8 bfrag = Wp[(kt * 8 + nt) * 64 + lane];
      acc[0][nt] = __builtin_amdgcn_mfma_f32_16x16x32_bf16(a0, bfrag, acc[0][nt], 0, 0, 0);
      acc[1][nt] = __builtin_amdgcn_mfma_f32_16x16x32_bf16(a1, bfrag, acc[1][nt], 0, 0, 0);
    }
  }

  float bov[8], wfv[8];
  #pragma unroll
  for (int nt = 0; nt < 8; ++nt) { bov[nt] = bo[nt * 16 + ln]; wfv[nt] = Wf[nt * 16 + ln]; }
  float bfs = bf_[0];

  #pragma unroll
  for (int mt = 0; mt < 2; ++mt) {
    #pragma unroll
    for (int r = 0; r < 4; ++r) {
      int row = n0 + mt * 16 + q * 4 + r;
      float partial = 0.f;
      if (row < N) {
        #pragma unroll
        for (int nt = 0; nt < 8; ++nt) {
          int col = nt * 16 + ln;
          float o = featsIn[(size_t)row * 128 + col] + acc[mt][nt][r] + bov[nt];
          partial += o * wfv[nt];
        }
      }
      partial += __shfl_xor(partial, 1);
      partial += __shfl_xor(partial, 2);
      partial += __shfl_xor(partial, 4);
      partial += __shfl_xor(partial, 8);
      if (ln == 0 && row < N) out[row] = partial + bfs;
    }
  }
}

// ---------------------------------------------------------------------------
extern "C" void kernel_launch(void* const* d_in, const int* in_sizes, int n_in,
                              void* d_out, int out_size, void* d_ws, size_t ws_size,
                              hipStream_t stream)
{
  const float* interpolated = (const float*)d_in[0];
  const float* add_info     = (const float*)d_in[1];
  const int*   nbr          = (const int*)d_in[2];
  const int*   segs         = (const int*)d_in[3];
  const float* Wb0 = (const float*)d_in[4];
  const float* bb0 = (const float*)d_in[5];
  const float* Wo0 = (const float*)d_in[6];
  const float* bo0 = (const float*)d_in[7];
  const float* Wb1 = (const float*)d_in[8];
  const float* bb1 = (const float*)d_in[9];
  const float* Wo1 = (const float*)d_in[10];
  const float* bo1 = (const float*)d_in[11];
  const float* Wf  = (const float*)d_in[12];
  const float* bf_ = (const float*)d_in[13];

  const int N = in_sizes[0] / 128;
  const int E = in_sizes[2];
  float* out = (float*)d_out;

  // workspace layout
  float* pooled = (float*)d_ws;                              // N*128 f32
  float* featsB = pooled + (size_t)N * 128;                  // N*128 f32
  bf16_t* Xbf       = (bf16_t*)(featsB + (size_t)N * 128);   // N*128 bf16
  bf16_t* featsB_bf = Xbf + (size_t)N * 128;                 // N*128 bf16
  bf16_t* Ybf       = featsB_bf + (size_t)N * 128;           // N*128 bf16
  bf16_t* Wtpk0 = Ybf + (size_t)N * 128;                     // 16384
  bf16_t* Wtpk1 = Wtpk0 + 4 * 8 * 64 * 8;                    // 16384
  bf16_t* Wopk0 = Wtpk1 + 4 * 8 * 64 * 8;                    // 16384
  bf16_t* Wopk1 = Wopk0 + 4 * 8 * 64 * 8;                    // 16384

  const int ugrid = (N + 127) / 128;
  const int egrid = (E + CH * 4 - 1) / (CH * 4);             // 4 waves x CH edges
  const int cgrid = ((N * 128) / 4 + 255) / 256;

  // prep: pack Wb_top (rows 0..127) and Wo weights; convert feats to bf16
  pack_w_kernel<<<64, 256, 0, stream>>>(Wb0, Wtpk0, 128, 4);
  pack_w_kernel<<<64, 256, 0, stream>>>(Wb1, Wtpk1, 128, 4);
  pack_w_kernel<<<64, 256, 0, stream>>>(Wo0, Wopk0, 128, 4);
  pack_w_kernel<<<64, 256, 0, stream>>>(Wo1, Wopk1, 128, 4);
  convert_bf16_kernel<<<cgrid, 256, 0, stream>>>(interpolated, Xbf, N * 128);

  // block 0
  yproj_mfma<<<ugrid, 256, 0, stream>>>(Xbf, Wtpk0, Ybf, pooled, N);
  edge_stream<<<egrid, 256, 0, stream>>>(Ybf, Wb0, bb0, add_info, nbr, segs,
                                         pooled, E);
  update_mfma<<<ugrid, 256, 0, stream>>>(interpolated, pooled, Wopk0, bo0,
                                         featsB, featsB_bf, N);

  // block 1
  yproj_mfma<<<ugrid, 256, 0, stream>>>(featsB_bf, Wtpk1, Ybf, pooled, N);
  edge_stream<<<egrid, 256, 0, stream>>>(Ybf, Wb1, bb1, add_info, nbr, segs,
                                         pooled, E);
  update_final_mfma<<<ugrid, 256, 0, stream>>>(featsB, pooled, Wopk1, bo1,
                                               Wf, bf_, out, N);
}

// Round 9
// 324.804 us; speedup vs baseline: 1.5533x; 1.5533x over previous
//
#include <hip/hip_runtime.h>
#include <limits.h>
#include <cstdint>

typedef __bf16 bf16_t;
typedef __attribute__((ext_vector_type(8))) __bf16 bf16x8;
typedef __attribute__((ext_vector_type(4))) float f32x4;

#define CH 64     // edges per wave in edge_stream (E=1.6M -> exact fit)

__device__ __forceinline__ float rlf(float v, int l) {
  return __int_as_float(__builtin_amdgcn_readlane(__float_as_int(v), l));
}

// ---------------------------------------------------------------------------
__global__ void convert_bf16_kernel(const float* __restrict__ in,
                                    bf16_t* __restrict__ out, int n) {
  int i = (blockIdx.x * blockDim.x + threadIdx.x) * 4;
  if (i < n) {
    float4 v = *reinterpret_cast<const float4*>(in + i);
    bf16_t o0 = (bf16_t)v.x, o1 = (bf16_t)v.y, o2 = (bf16_t)v.z, o3 = (bf16_t)v.w;
    ushort4 u;
    u.x = __builtin_bit_cast(unsigned short, o0);
    u.y = __builtin_bit_cast(unsigned short, o1);
    u.z = __builtin_bit_cast(unsigned short, o2);
    u.w = __builtin_bit_cast(unsigned short, o3);
    *reinterpret_cast<ushort4*>(out + i) = u;
  }
}

// ---------------------------------------------------------------------------
// Pack W (KROWS x 128 fp32) -> MFMA B-frag order, bf16, K padded to KTILES*32.
// ---------------------------------------------------------------------------
__global__ void pack_w_kernel(const float* __restrict__ W,
                              bf16_t* __restrict__ packed, int KROWS, int KTILES) {
  int idx = blockIdx.x * blockDim.x + threadIdx.x;
  if (idx >= KTILES * 8 * 64 * 8) return;
  int j  = idx & 7;
  int L  = (idx >> 3) & 63;
  int nt = (idx >> 9) & 7;
  int kt = idx >> 12;
  int k = kt * 32 + (L >> 4) * 8 + j;
  int n = nt * 16 + (L & 15);
  float v = (k < KROWS) ? W[(size_t)k * 128 + n] : 0.f;
  packed[idx] = (bf16_t)v;
}

// ---------------------------------------------------------------------------
// Y = Xbf @ Wtop (N x 128, K=128) via bf16 MFMA, bf16 output.
// Also zeroes the pooled buffer for this WG's rows (fuses zero_kernel).
// ---------------------------------------------------------------------------
__global__ __launch_bounds__(256, 4) void yproj_mfma(
    const bf16_t* __restrict__ Xbf, const bf16_t* __restrict__ Wtpk,
    bf16_t* __restrict__ Ybf, float* __restrict__ pooled, int N)
{
  const int tid = threadIdx.x;
  const int base = blockIdx.x * 128;

  float4 z = make_float4(0.f, 0.f, 0.f, 0.f);
  #pragma unroll
  for (int i = 0; i < 16; ++i) {
    int idx = tid + i * 256;
    int row = base + (idx >> 5);
    if (row < N)
      reinterpret_cast<float4*>(pooled)[(size_t)row * 32 + (idx & 31)] = z;
  }

  const int lane = tid & 63;
  const int w    = tid >> 6;
  const int q    = lane >> 4;
  const int ln   = lane & 15;
  const int n0   = base + w * 32;

  int r0 = n0 + ln, r1 = n0 + 16 + ln;
  int r0c = (r0 < N) ? r0 : (N - 1);
  int r1c = (r1 < N) ? r1 : (N - 1);
  const bf16_t* x0 = Xbf + (size_t)r0c * 128 + q * 8;
  const bf16_t* x1 = Xbf + (size_t)r1c * 128 + q * 8;

  f32x4 acc[2][8];
  #pragma unroll
  for (int mt = 0; mt < 2; ++mt)
    #pragma unroll
    for (int nt = 0; nt < 8; ++nt)
      #pragma unroll
      for (int r = 0; r < 4; ++r) acc[mt][nt][r] = 0.f;

  const bf16x8* Wp = reinterpret_cast<const bf16x8*>(Wtpk);
  #pragma unroll
  for (int kt = 0; kt < 4; ++kt) {
    bf16x8 a0 = *reinterpret_cast<const bf16x8*>(x0 + kt * 32);
    bf16x8 a1 = *reinterpret_cast<const bf16x8*>(x1 + kt * 32);
    #pragma unroll
    for (int nt = 0; nt < 8; ++nt) {
      bf16x8 bfrag = Wp[(kt * 8 + nt) * 64 + lane];
      acc[0][nt] = __builtin_amdgcn_mfma_f32_16x16x32_bf16(a0, bfrag, acc[0][nt], 0, 0, 0);
      acc[1][nt] = __builtin_amdgcn_mfma_f32_16x16x32_bf16(a1, bfrag, acc[1][nt], 0, 0, 0);
    }
  }

  #pragma unroll
  for (int mt = 0; mt < 2; ++mt) {
    #pragma unroll
    for (int r = 0; r < 4; ++r) {
      int row = n0 + mt * 16 + q * 4 + r;
      if (row < N) {
        #pragma unroll
        for (int nt = 0; nt < 8; ++nt) {
          int col = nt * 16 + ln;
          Ybf[(size_t)row * 128 + col] = (bf16_t)acc[mt][nt][r];
        }
      }
    }
  }
}

// ---------------------------------------------------------------------------
// Edge pass, streaming. NO SMEM IN HOT LOOP: per-edge metadata comes from
// chunk-header cooperative VECTOR loads (nbr/segs: 1 coalesced load each;
// add_info: 4) broadcast per-edge via v_readlane (VALU, no wait). SMEM loads
// return out-of-order -> force lgkmcnt(0) drains per edge, which was the
// round-7/8 stall. Y gathers keep round-7's batch-of-8 ring (in-order vmcnt,
// fine-grained waits). ReLU folded into running max.
// ---------------------------------------------------------------------------
__global__ __launch_bounds__(256) void edge_stream(
    const bf16_t* __restrict__ Y,        // N x 128 bf16
    const float* __restrict__ Wb,        // 132 x 128; rows 128..131 = Wbot
    const float* __restrict__ bb,        // 128
    const float* __restrict__ add_info,  // E x 4
    const int* __restrict__ nbr, const int* __restrict__ segs,
    float* __restrict__ pooled, int E)
{
  const int lane = threadIdx.x & 63;
  const int wv = __builtin_amdgcn_readfirstlane(threadIdx.x >> 6);  // SGPR
  const int e0 = (blockIdx.x * 4 + wv) * CH;                        // uniform
  if (e0 >= E) return;
  const int c0 = lane * 2;

  float wka[4], wkb[4];
  #pragma unroll
  for (int k = 0; k < 4; ++k) {
    wka[k] = Wb[(size_t)(128 + k) * 128 + c0];
    wkb[k] = Wb[(size_t)(128 + k) * 128 + c0 + 1];
  }
  const float bb0 = bb[c0], bb1 = bb[c0 + 1];

  unsigned* pooled_u = reinterpret_cast<unsigned*>(pooled);
  float v0 = 0.f, v1 = 0.f;

  if (e0 + CH <= E) {
    // ---- chunk header: cooperative vector loads (one vmcnt wait total) ----
    int v_nbr = nbr[e0 + lane];                 // lane l: nbr of edge e0+l
    int v_sg  = segs[e0 + lane];                // lane l: seg of edge e0+l
    float v_ai[4];
    #pragma unroll
    for (int r = 0; r < 4; ++r)                 // 256 floats = 64 edges x 4
      v_ai[r] = add_info[(size_t)e0 * 4 + r * 64 + lane];

    int cur = __builtin_amdgcn_readlane(v_sg, 0);

    // ---- Y ring: batch of 8 (round-7 proven scheduling) ----
    unsigned ycur[8], ynxt[8];
    #pragma unroll
    for (int j = 0; j < 8; ++j) {
      int rn = __builtin_amdgcn_readlane(v_nbr, j);
      ycur[j] = *((const unsigned*)(Y + (size_t)rn * 128) + lane);
    }

    #pragma unroll
    for (int g = 0; g < CH / 8; ++g) {
      if (g < CH / 8 - 1) {
        #pragma unroll
        for (int j = 0; j < 8; ++j) {
          int rn = __builtin_amdgcn_readlane(v_nbr, (g + 1) * 8 + j);
          ynxt[j] = *((const unsigned*)(Y + (size_t)rn * 128) + lane);
        }
      }
      #pragma unroll
      for (int j = 0; j < 8; ++j) {
        const int i = g * 8 + j;                              // 0..63, constant
        int sg = __builtin_amdgcn_readlane(v_sg, i);          // SGPR
        if (sg != cur) {                                      // scalar branch
          if (v0 > 0.f) atomicMax(&pooled_u[(size_t)cur * 128 + c0], __float_as_uint(v0));
          if (v1 > 0.f) atomicMax(&pooled_u[(size_t)cur * 128 + c0 + 1], __float_as_uint(v1));
          v0 = 0.f; v1 = 0.f; cur = sg;
        }
        unsigned yb = ycur[j];
        float y0 = __uint_as_float(yb << 16);
        float y1 = __uint_as_float(yb & 0xffff0000u);
        float a0 = rlf(v_ai[i >> 4], (i * 4 + 0) & 63);       // SGPR broadcast
        float a1 = rlf(v_ai[i >> 4], (i * 4 + 1) & 63);
        float a2 = rlf(v_ai[i >> 4], (i * 4 + 2) & 63);
        float a3 = rlf(v_ai[i >> 4], (i * 4 + 3) & 63);
        float t0 = y0 + bb0 + a0 * wka[0] + a1 * wka[1] + a2 * wka[2] + a3 * wka[3];
        float t1 = y1 + bb1 + a0 * wkb[0] + a1 * wkb[1] + a2 * wkb[2] + a3 * wkb[3];
        v0 = fmaxf(v0, t0);    // ReLU folded: v init 0
        v1 = fmaxf(v1, t1);
      }
      #pragma unroll
      for (int j = 0; j < 8; ++j) ycur[j] = ynxt[j];
    }
    if (v0 > 0.f) atomicMax(&pooled_u[(size_t)cur * 128 + c0], __float_as_uint(v0));
    if (v1 > 0.f) atomicMax(&pooled_u[(size_t)cur * 128 + c0 + 1], __float_as_uint(v1));
  } else {
    // ---- tail path (rare; uniform control flow, scalar loads OK) ----
    int cur = segs[e0];
    const int rem = E - e0;
    for (int i = 0; i < rem; ++i) {
      const int e = e0 + i;
      int sg = segs[e];
      if (sg != cur) {
        if (v0 > 0.f) atomicMax(&pooled_u[(size_t)cur * 128 + c0], __float_as_uint(v0));
        if (v1 > 0.f) atomicMax(&pooled_u[(size_t)cur * 128 + c0 + 1], __float_as_uint(v1));
        v0 = 0.f; v1 = 0.f; cur = sg;
      }
      unsigned yb = *reinterpret_cast<const unsigned*>(
          Y + (size_t)nbr[e] * 128 + c0);
      float y0 = __uint_as_float(yb << 16);
      float y1 = __uint_as_float(yb & 0xffff0000u);
      const float* ai = add_info + (size_t)e * 4;
      float a0 = ai[0], a1 = ai[1], a2 = ai[2], a3 = ai[3];
      float t0 = y0 + bb0 + a0 * wka[0] + a1 * wka[1] + a2 * wka[2] + a3 * wka[3];
      float t1 = y1 + bb1 + a0 * wkb[0] + a1 * wkb[1] + a2 * wkb[2] + a3 * wkb[3];
      v0 = fmaxf(v0, t0);
      v1 = fmaxf(v1, t1);
    }
    if (v0 > 0.f) atomicMax(&pooled_u[(size_t)cur * 128 + c0], __float_as_uint(v0));
    if (v1 > 0.f) atomicMax(&pooled_u[(size_t)cur * 128 + c0 + 1], __float_as_uint(v1));
  }
}

// ---------------------------------------------------------------------------
// featsOut = featsIn + pooled @ Wo + bo via bf16 MFMA; emits bf16 copy.
// ---------------------------------------------------------------------------
__global__ __launch_bounds__(256, 4) void update_mfma(
    const float* __restrict__ featsIn, const float* __restrict__ pooled,
    const bf16_t* __restrict__ Wopk, const float* __restrict__ bo,
    float* __restrict__ featsOut, bf16_t* __restrict__ featsOutBf, int N)
{
  const int tid  = threadIdx.x;
  const int lane = tid & 63;
  const int w    = tid >> 6;
  const int q    = lane >> 4;
  const int ln   = lane & 15;
  const int n0   = blockIdx.x * 128 + w * 32;

  int r0 = n0 + ln, r1 = n0 + 16 + ln;
  int r0c = (r0 < N) ? r0 : (N - 1);
  int r1c = (r1 < N) ? r1 : (N - 1);
  const float* p0 = pooled + (size_t)r0c * 128 + q * 8;
  const float* p1 = pooled + (size_t)r1c * 128 + q * 8;

  f32x4 acc[2][8];
  #pragma unroll
  for (int mt = 0; mt < 2; ++mt)
    #pragma unroll
    for (int nt = 0; nt < 8; ++nt)
      #pragma unroll
      for (int r = 0; r < 4; ++r) acc[mt][nt][r] = 0.f;

  const bf16x8* Wp = reinterpret_cast<const bf16x8*>(Wopk);
  #pragma unroll
  for (int kt = 0; kt < 4; ++kt) {
    float4 f0a = *reinterpret_cast<const float4*>(p0 + kt * 32);
    float4 f0b = *reinterpret_cast<const float4*>(p0 + kt * 32 + 4);
    float4 f1a = *reinterpret_cast<const float4*>(p1 + kt * 32);
    float4 f1b = *reinterpret_cast<const float4*>(p1 + kt * 32 + 4);
    bf16x8 a0, a1;
    a0[0] = (bf16_t)f0a.x; a0[1] = (bf16_t)f0a.y; a0[2] = (bf16_t)f0a.z; a0[3] = (bf16_t)f0a.w;
    a0[4] = (bf16_t)f0b.x; a0[5] = (bf16_t)f0b.y; a0[6] = (bf16_t)f0b.z; a0[7] = (bf16_t)f0b.w;
    a1[0] = (bf16_t)f1a.x; a1[1] = (bf16_t)f1a.y; a1[2] = (bf16_t)f1a.z; a1[3] = (bf16_t)f1a.w;
    a1[4] = (bf16_t)f1b.x; a1[5] = (bf16_t)f1b.y; a1[6] = (bf16_t)f1b.z; a1[7] = (bf16_t)f1b.w;
    #pragma unroll
    for (int nt = 0; nt < 8; ++nt) {
      bf16x8 bfrag = Wp[(kt * 8 + nt) * 64 + lane];
      acc[0][nt] = __builtin_amdgcn_mfma_f32_16x16x32_bf16(a0, bfrag, acc[0][nt], 0, 0, 0);
      acc[1][nt] = __builtin_amdgcn_mfma_f32_16x16x32_bf16(a1, bfrag, acc[1][nt], 0, 0, 0);
    }
  }

  float bov[8];
  #pragma unroll
  for (int nt = 0; nt < 8; ++nt) bov[nt] = bo[nt * 16 + ln];

  #pragma unroll
  for (int mt = 0; mt < 2; ++mt) {
    #pragma unroll
    for (int r = 0; r < 4; ++r) {
      int row = n0 + mt * 16 + q * 4 + r;
      if (row < N) {
        #pragma unroll
        for (int nt = 0; nt < 8; ++nt) {
          int col = nt * 16 + ln;
          float o = featsIn[(size_t)row * 128 + col] + acc[mt][nt][r] + bov[nt];
          featsOut[(size_t)row * 128 + col] = o;
          featsOutBf[(size_t)row * 128 + col] = (bf16_t)o;
        }
      }
    }
  }
}

// ---------------------------------------------------------------------------
// Block-1 update FUSED with final projection:
// out[n] = (featsIn[n] + pooled[n] @ Wo + bo) . Wf + bf
// ---------------------------------------------------------------------------
__global__ __launch_bounds__(256, 4) void update_final_mfma(
    const float* __restrict__ featsIn, const float* __restrict__ pooled,
    const bf16_t* __restrict__ Wopk, const float* __restrict__ bo,
    const float* __restrict__ Wf, const float* __restrict__ bf_,
    float* __restrict__ out, int N)
{
  const int tid  = threadIdx.x;
  const int lane = tid & 63;
  const int w    = tid >> 6;
  const int q    = lane >> 4;
  const int ln   = lane & 15;
  const int n0   = blockIdx.x * 128 + w * 32;

  int r0 = n0 + ln, r1 = n0 + 16 + ln;
  int r0c = (r0 < N) ? r0 : (N - 1);
  int r1c = (r1 < N) ? r1 : (N - 1);
  const float* p0 = pooled + (size_t)r0c * 128 + q * 8;
  const float* p1 = pooled + (size_t)r1c * 128 + q * 8;

  f32x4 acc[2][8];
  #pragma unroll
  for (int mt = 0; mt < 2; ++mt)
    #pragma unroll
    for (int nt = 0; nt < 8; ++nt)
      #pragma unroll
      for (int r = 0; r < 4; ++r) acc[mt][nt][r] = 0.f;

  const bf16x8* Wp = reinterpret_cast<const bf16x8*>(Wopk);
  #pragma unroll
  for (int kt = 0; kt < 4; ++kt) {
    float4 f0a = *reinterpret_cast<const float4*>(p0 + kt * 32);
    float4 f0b = *reinterpret_cast<const float4*>(p0 + kt * 32 + 4);
    float4 f1a = *reinterpret_cast<const float4*>(p1 + kt * 32);
    float4 f1b = *reinterpret_cast<const float4*>(p1 + kt * 32 + 4);
    bf16x8 a0, a1;
    a0[0] = (bf16_t)f0a.x; a0[1] = (bf16_t)f0a.y; a0[2] = (bf16_t)f0a.z; a0[3] = (bf16_t)f0a.w;
    a0[4] = (bf16_t)f0b.x; a0[5] = (bf16_t)f0b.y; a0[6] = (bf16_t)f0b.z; a0[7] = (bf16_t)f0b.w;
    a1[0] = (bf16_t)f1a.x; a1[1] = (bf16_t)f1a.y; a1[2] = (bf16_t)f1a.z; a1[3] = (bf16_t)f1a.w;
    a1[4] = (bf16_t)f1b.x; a1[5] = (bf16_t)f1b.y; a1[6] = (bf16_t)f1b.z; a1[7] = (bf16_t)f1b.w;
    #pragma unroll
    for (int nt = 0; nt < 8; ++nt) {
      bf16x8 bfrag = Wp[(kt * 8 + nt) * 64 + lane];
      acc[0][nt] = __builtin_amdgcn_mfma_f32_16x16x32_bf16(a0, bfrag, acc[0][nt], 0, 0, 0);
      acc[1][nt] = __builtin_amdgcn_mfma_f32_16x16x32_bf16(a1, bfrag, acc[1][nt], 0, 0, 0);
    }
  }

  float bov[8], wfv[8];
  #pragma unroll
  for (int nt = 0; nt < 8; ++nt) { bov[nt] = bo[nt * 16 + ln]; wfv[nt] = Wf[nt * 16 + ln]; }
  float bfs = bf_[0];

  #pragma unroll
  for (int mt = 0; mt < 2; ++mt) {
    #pragma unroll
    for (int r = 0; r < 4; ++r) {
      int row = n0 + mt * 16 + q * 4 + r;
      float partial = 0.f;
      if (row < N) {
        #pragma unroll
        for (int nt = 0; nt < 8; ++nt) {
          int col = nt * 16 + ln;
          float o = featsIn[(size_t)row * 128 + col] + acc[mt][nt][r] + bov[nt];
          partial += o * wfv[nt];
        }
      }
      partial += __shfl_xor(partial, 1);
      partial += __shfl_xor(partial, 2);
      partial += __shfl_xor(partial, 4);
      partial += __shfl_xor(partial, 8);
      if (ln == 0 && row < N) out[row] = partial + bfs;
    }
  }
}

// ---------------------------------------------------------------------------
extern "C" void kernel_launch(void* const* d_in, const int* in_sizes, int n_in,
                              void* d_out, int out_size, void* d_ws, size_t ws_size,
                              hipStream_t stream)
{
  const float* interpolated = (const float*)d_in[0];
  const float* add_info     = (const float*)d_in[1];
  const int*   nbr          = (const int*)d_in[2];
  const int*   segs         = (const int*)d_in[3];
  const float* Wb0 = (const float*)d_in[4];
  const float* bb0 = (const float*)d_in[5];
  const float* Wo0 = (const float*)d_in[6];
  const float* bo0 = (const float*)d_in[7];
  const float* Wb1 = (const float*)d_in[8];
  const float* bb1 = (const float*)d_in[9];
  const float* Wo1 = (const float*)d_in[10];
  const float* bo1 = (const float*)d_in[11];
  const float* Wf  = (const float*)d_in[12];
  const float* bf_ = (const float*)d_in[13];

  const int N = in_sizes[0] / 128;
  const int E = in_sizes[2];
  float* out = (float*)d_out;

  // workspace layout
  float* pooled = (float*)d_ws;                              // N*128 f32
  float* featsB = pooled + (size_t)N * 128;                  // N*128 f32
  bf16_t* Xbf       = (bf16_t*)(featsB + (size_t)N * 128);   // N*128 bf16
  bf16_t* featsB_bf = Xbf + (size_t)N * 128;                 // N*128 bf16
  bf16_t* Ybf       = featsB_bf + (size_t)N * 128;           // N*128 bf16
  bf16_t* Wtpk0 = Ybf + (size_t)N * 128;                     // 16384
  bf16_t* Wtpk1 = Wtpk0 + 4 * 8 * 64 * 8;                    // 16384
  bf16_t* Wopk0 = Wtpk1 + 4 * 8 * 64 * 8;                    // 16384
  bf16_t* Wopk1 = Wopk0 + 4 * 8 * 64 * 8;                    // 16384

  const int ugrid = (N + 127) / 128;
  const int egrid = (E + CH * 4 - 1) / (CH * 4);             // 4 waves x CH edges
  const int cgrid = ((N * 128) / 4 + 255) / 256;

  // prep: pack Wb_top (rows 0..127) and Wo weights; convert feats to bf16
  pack_w_kernel<<<64, 256, 0, stream>>>(Wb0, Wtpk0, 128, 4);
  pack_w_kernel<<<64, 256, 0, stream>>>(Wb1, Wtpk1, 128, 4);
  pack_w_kernel<<<64, 256, 0, stream>>>(Wo0, Wopk0, 128, 4);
  pack_w_kernel<<<64, 256, 0, stream>>>(Wo1, Wopk1, 128, 4);
  convert_bf16_kernel<<<cgrid, 256, 0, stream>>>(interpolated, Xbf, N * 128);

  // block 0
  yproj_mfma<<<ugrid, 256, 0, stream>>>(Xbf, Wtpk0, Ybf, pooled, N);
  edge_stream<<<egrid, 256, 0, stream>>>(Ybf, Wb0, bb0, add_info, nbr, segs,
                                         pooled, E);
  update_mfma<<<ugrid, 256, 0, stream>>>(interpolated, pooled, Wopk0, bo0,
                                         featsB, featsB_bf, N);

  // block 1
  yproj_mfma<<<ugrid, 256, 0, stream>>>(featsB_bf, Wtpk1, Ybf, pooled, N);
  edge_stream<<<egrid, 256, 0, stream>>>(Ybf, Wb1, bb1, add_info, nbr, segs,
                                         pooled, E);
  update_final_mfma<<<ugrid, 256, 0, stream>>>(featsB, pooled, Wopk1, bo1,
                                               Wf, bf_, out, N);
}

// Round 10
// 308.017 us; speedup vs baseline: 1.6379x; 1.0545x over previous
//
#include <hip/hip_runtime.h>
#include <limits.h>
#include <cstdint>

typedef __bf16 bf16_t;
typedef __attribute__((ext_vector_type(8))) __bf16 bf16x8;
typedef __attribute__((ext_vector_type(4))) float f32x4;
typedef __attribute__((ext_vector_type(2))) float f32x2;

#define CH 64     // edges per wave in edge_stream

__device__ __forceinline__ float rlf(float v, int l) {
  return __int_as_float(__builtin_amdgcn_readlane(__float_as_int(v), l));
}

// ---------------------------------------------------------------------------
// Pack all four 128x128 weight matrices -> MFMA B-frag order, one launch.
// packed[((kt*8+nt)*64+L)*8+j] = W[kt*32+(L>>4)*8+j][nt*16+(L&15)]
// ---------------------------------------------------------------------------
struct PackArgs {
  const float* W[4];
  bf16_t* P[4];
};

__global__ __launch_bounds__(256) void pack4_kernel(PackArgs args) {
  int idx = blockIdx.x * blockDim.x + threadIdx.x;   // 4 * 16384
  int which = idx >> 14;
  int r = idx & 16383;
  int j  = r & 7;
  int L  = (r >> 3) & 63;
  int nt = (r >> 9) & 7;
  int kt = r >> 12;
  int k = kt * 32 + (L >> 4) * 8 + j;
  int n = nt * 16 + (L & 15);
  args.P[which][r] = (bf16_t)args.W[which][(size_t)k * 128 + n];
}

// ---------------------------------------------------------------------------
// Y = X @ Wtop via bf16 MFMA. X is fp32 (converted in-register). Also zeroes
// pooled rows for this WG (fuses zero_kernel).
// ---------------------------------------------------------------------------
__global__ __launch_bounds__(256, 4) void yproj_f32(
    const float* __restrict__ X, const bf16_t* __restrict__ Wtpk,
    bf16_t* __restrict__ Ybf, float* __restrict__ pooled, int N)
{
  const int tid = threadIdx.x;
  const int base = blockIdx.x * 128;

  float4 z = make_float4(0.f, 0.f, 0.f, 0.f);
  #pragma unroll
  for (int i = 0; i < 16; ++i) {
    int idx = tid + i * 256;
    int row = base + (idx >> 5);
    if (row < N)
      reinterpret_cast<float4*>(pooled)[(size_t)row * 32 + (idx & 31)] = z;
  }

  const int lane = tid & 63;
  const int w    = tid >> 6;
  const int q    = lane >> 4;
  const int ln   = lane & 15;
  const int n0   = base + w * 32;

  int r0 = n0 + ln, r1 = n0 + 16 + ln;
  int r0c = (r0 < N) ? r0 : (N - 1);
  int r1c = (r1 < N) ? r1 : (N - 1);
  const float* x0 = X + (size_t)r0c * 128 + q * 8;
  const float* x1 = X + (size_t)r1c * 128 + q * 8;

  f32x4 acc[2][8];
  #pragma unroll
  for (int mt = 0; mt < 2; ++mt)
    #pragma unroll
    for (int nt = 0; nt < 8; ++nt)
      #pragma unroll
      for (int r = 0; r < 4; ++r) acc[mt][nt][r] = 0.f;

  const bf16x8* Wp = reinterpret_cast<const bf16x8*>(Wtpk);
  #pragma unroll
  for (int kt = 0; kt < 4; ++kt) {
    float4 f0a = *reinterpret_cast<const float4*>(x0 + kt * 32);
    float4 f0b = *reinterpret_cast<const float4*>(x0 + kt * 32 + 4);
    float4 f1a = *reinterpret_cast<const float4*>(x1 + kt * 32);
    float4 f1b = *reinterpret_cast<const float4*>(x1 + kt * 32 + 4);
    bf16x8 a0, a1;
    a0[0] = (bf16_t)f0a.x; a0[1] = (bf16_t)f0a.y; a0[2] = (bf16_t)f0a.z; a0[3] = (bf16_t)f0a.w;
    a0[4] = (bf16_t)f0b.x; a0[5] = (bf16_t)f0b.y; a0[6] = (bf16_t)f0b.z; a0[7] = (bf16_t)f0b.w;
    a1[0] = (bf16_t)f1a.x; a1[1] = (bf16_t)f1a.y; a1[2] = (bf16_t)f1a.z; a1[3] = (bf16_t)f1a.w;
    a1[4] = (bf16_t)f1b.x; a1[5] = (bf16_t)f1b.y; a1[6] = (bf16_t)f1b.z; a1[7] = (bf16_t)f1b.w;
    #pragma unroll
    for (int nt = 0; nt < 8; ++nt) {
      bf16x8 bfrag = Wp[(kt * 8 + nt) * 64 + lane];
      acc[0][nt] = __builtin_amdgcn_mfma_f32_16x16x32_bf16(a0, bfrag, acc[0][nt], 0, 0, 0);
      acc[1][nt] = __builtin_amdgcn_mfma_f32_16x16x32_bf16(a1, bfrag, acc[1][nt], 0, 0, 0);
    }
  }

  #pragma unroll
  for (int mt = 0; mt < 2; ++mt) {
    #pragma unroll
    for (int r = 0; r < 4; ++r) {
      int row = n0 + mt * 16 + q * 4 + r;
      if (row < N) {
        #pragma unroll
        for (int nt = 0; nt < 8; ++nt) {
          int col = nt * 16 + ln;
          Ybf[(size_t)row * 128 + col] = (bf16_t)acc[mt][nt][r];
        }
      }
    }
  }
}

// ---------------------------------------------------------------------------
// Same but X already bf16 (block 1: reads featsB_bf written by update_mfma).
// ---------------------------------------------------------------------------
__global__ __launch_bounds__(256, 4) void yproj_bf16(
    const bf16_t* __restrict__ Xbf, const bf16_t* __restrict__ Wtpk,
    bf16_t* __restrict__ Ybf, float* __restrict__ pooled, int N)
{
  const int tid = threadIdx.x;
  const int base = blockIdx.x * 128;

  float4 z = make_float4(0.f, 0.f, 0.f, 0.f);
  #pragma unroll
  for (int i = 0; i < 16; ++i) {
    int idx = tid + i * 256;
    int row = base + (idx >> 5);
    if (row < N)
      reinterpret_cast<float4*>(pooled)[(size_t)row * 32 + (idx & 31)] = z;
  }

  const int lane = tid & 63;
  const int w    = tid >> 6;
  const int q    = lane >> 4;
  const int ln   = lane & 15;
  const int n0   = base + w * 32;

  int r0 = n0 + ln, r1 = n0 + 16 + ln;
  int r0c = (r0 < N) ? r0 : (N - 1);
  int r1c = (r1 < N) ? r1 : (N - 1);
  const bf16_t* x0 = Xbf + (size_t)r0c * 128 + q * 8;
  const bf16_t* x1 = Xbf + (size_t)r1c * 128 + q * 8;

  f32x4 acc[2][8];
  #pragma unroll
  for (int mt = 0; mt < 2; ++mt)
    #pragma unroll
    for (int nt = 0; nt < 8; ++nt)
      #pragma unroll
      for (int r = 0; r < 4; ++r) acc[mt][nt][r] = 0.f;

  const bf16x8* Wp = reinterpret_cast<const bf16x8*>(Wtpk);
  #pragma unroll
  for (int kt = 0; kt < 4; ++kt) {
    bf16x8 a0 = *reinterpret_cast<const bf16x8*>(x0 + kt * 32);
    bf16x8 a1 = *reinterpret_cast<const bf16x8*>(x1 + kt * 32);
    #pragma unroll
    for (int nt = 0; nt < 8; ++nt) {
      bf16x8 bfrag = Wp[(kt * 8 + nt) * 64 + lane];
      acc[0][nt] = __builtin_amdgcn_mfma_f32_16x16x32_bf16(a0, bfrag, acc[0][nt], 0, 0, 0);
      acc[1][nt] = __builtin_amdgcn_mfma_f32_16x16x32_bf16(a1, bfrag, acc[1][nt], 0, 0, 0);
    }
  }

  #pragma unroll
  for (int mt = 0; mt < 2; ++mt) {
    #pragma unroll
    for (int r = 0; r < 4; ++r) {
      int row = n0 + mt * 16 + q * 4 + r;
      if (row < N) {
        #pragma unroll
        for (int nt = 0; nt < 8; ++nt) {
          int col = nt * 16 + ln;
          Ybf[(size_t)row * 128 + col] = (bf16_t)acc[mt][nt][r];
        }
      }
    }
  }
}

// ---------------------------------------------------------------------------
// Edge pass. Round-9 structure (chunk-header vector loads + readlane
// broadcast, zero SMEM in hot loop) + PACKED fp32 math (f32x2 ->
// v_pk_fma/add/max) + ping-pong Y buffers (no ring-copy movs).
// ---------------------------------------------------------------------------
__global__ __launch_bounds__(256) void edge_stream(
    const bf16_t* __restrict__ Y,        // N x 128 bf16
    const float* __restrict__ Wb,        // 132 x 128; rows 128..131 = Wbot
    const float* __restrict__ bb,        // 128
    const float* __restrict__ add_info,  // E x 4
    const int* __restrict__ nbr, const int* __restrict__ segs,
    float* __restrict__ pooled, int E)
{
  const int lane = threadIdx.x & 63;
  const int wv = __builtin_amdgcn_readfirstlane(threadIdx.x >> 6);  // SGPR
  const int e0 = (blockIdx.x * 4 + wv) * CH;                        // uniform
  if (e0 >= E) return;
  const int c0 = lane * 2;

  f32x2 wk[4];
  #pragma unroll
  for (int k = 0; k < 4; ++k) {
    wk[k].x = Wb[(size_t)(128 + k) * 128 + c0];
    wk[k].y = Wb[(size_t)(128 + k) * 128 + c0 + 1];
  }
  f32x2 bbv;
  bbv.x = bb[c0]; bbv.y = bb[c0 + 1];

  unsigned* pooled_u = reinterpret_cast<unsigned*>(pooled);
  f32x2 v; v.x = 0.f; v.y = 0.f;

  if (e0 + CH <= E) {
    // ---- chunk header: cooperative vector loads ----
    int v_nbr = nbr[e0 + lane];
    int v_sg  = segs[e0 + lane];
    float v_ai[4];
    #pragma unroll
    for (int r = 0; r < 4; ++r)
      v_ai[r] = add_info[(size_t)e0 * 4 + r * 64 + lane];

    int cur = __builtin_amdgcn_readlane(v_sg, 0);

    // ---- ping-pong Y buffers, batch of 8 ----
    unsigned ybuf[2][8];
    #pragma unroll
    for (int j = 0; j < 8; ++j) {
      int rn = __builtin_amdgcn_readlane(v_nbr, j);
      ybuf[0][j] = *((const unsigned*)(Y + (size_t)rn * 128) + lane);
    }

    #pragma unroll
    for (int g = 0; g < CH / 8; ++g) {
      if (g < CH / 8 - 1) {
        #pragma unroll
        for (int j = 0; j < 8; ++j) {
          int rn = __builtin_amdgcn_readlane(v_nbr, (g + 1) * 8 + j);
          ybuf[(g + 1) & 1][j] = *((const unsigned*)(Y + (size_t)rn * 128) + lane);
        }
      }
      #pragma unroll
      for (int j = 0; j < 8; ++j) {
        const int i = g * 8 + j;                              // constant
        int sg = __builtin_amdgcn_readlane(v_sg, i);
        if (sg != cur) {                                      // uniform branch
          if (v.x > 0.f) atomicMax(&pooled_u[(size_t)cur * 128 + c0], __float_as_uint(v.x));
          if (v.y > 0.f) atomicMax(&pooled_u[(size_t)cur * 128 + c0 + 1], __float_as_uint(v.y));
          v.x = 0.f; v.y = 0.f; cur = sg;
        }
        unsigned yb = ybuf[g & 1][j];
        f32x2 y;
        y.x = __uint_as_float(yb << 16);
        y.y = __uint_as_float(yb & 0xffff0000u);
        float a0 = rlf(v_ai[i >> 4], (i * 4 + 0) & 63);
        float a1 = rlf(v_ai[i >> 4], (i * 4 + 1) & 63);
        float a2 = rlf(v_ai[i >> 4], (i * 4 + 2) & 63);
        float a3 = rlf(v_ai[i >> 4], (i * 4 + 3) & 63);
        f32x2 t = bbv + a0 * wk[0];      // v_pk_fma_f32 chain
        t += a1 * wk[1];
        t += a2 * wk[2];
        t += a3 * wk[3];
        t += y;                           // v_pk_add_f32
        v.x = fmaxf(v.x, t.x);            // v_pk_max_f32 (pair)
        v.y = fmaxf(v.y, t.y);
      }
    }
    if (v.x > 0.f) atomicMax(&pooled_u[(size_t)cur * 128 + c0], __float_as_uint(v.x));
    if (v.y > 0.f) atomicMax(&pooled_u[(size_t)cur * 128 + c0 + 1], __float_as_uint(v.y));
  } else {
    // ---- tail path ----
    int cur = segs[e0];
    const int rem = E - e0;
    for (int i = 0; i < rem; ++i) {
      const int e = e0 + i;
      int sg = segs[e];
      if (sg != cur) {
        if (v.x > 0.f) atomicMax(&pooled_u[(size_t)cur * 128 + c0], __float_as_uint(v.x));
        if (v.y > 0.f) atomicMax(&pooled_u[(size_t)cur * 128 + c0 + 1], __float_as_uint(v.y));
        v.x = 0.f; v.y = 0.f; cur = sg;
      }
      unsigned yb = *reinterpret_cast<const unsigned*>(Y + (size_t)nbr[e] * 128 + c0);
      float y0 = __uint_as_float(yb << 16);
      float y1 = __uint_as_float(yb & 0xffff0000u);
      const float* ai = add_info + (size_t)e * 4;
      float a0 = ai[0], a1 = ai[1], a2 = ai[2], a3 = ai[3];
      float t0 = y0 + bbv.x + a0 * wk[0].x + a1 * wk[1].x + a2 * wk[2].x + a3 * wk[3].x;
      float t1 = y1 + bbv.y + a0 * wk[0].y + a1 * wk[1].y + a2 * wk[2].y + a3 * wk[3].y;
      v.x = fmaxf(v.x, t0);
      v.y = fmaxf(v.y, t1);
    }
    if (v.x > 0.f) atomicMax(&pooled_u[(size_t)cur * 128 + c0], __float_as_uint(v.x));
    if (v.y > 0.f) atomicMax(&pooled_u[(size_t)cur * 128 + c0 + 1], __float_as_uint(v.y));
  }
}

// ---------------------------------------------------------------------------
// featsOut = featsIn + pooled @ Wo + bo via bf16 MFMA; emits bf16 copy.
// ---------------------------------------------------------------------------
__global__ __launch_bounds__(256, 4) void update_mfma(
    const float* __restrict__ featsIn, const float* __restrict__ pooled,
    const bf16_t* __restrict__ Wopk, const float* __restrict__ bo,
    float* __restrict__ featsOut, bf16_t* __restrict__ featsOutBf, int N)
{
  const int tid  = threadIdx.x;
  const int lane = tid & 63;
  const int w    = tid >> 6;
  const int q    = lane >> 4;
  const int ln   = lane & 15;
  const int n0   = blockIdx.x * 128 + w * 32;

  int r0 = n0 + ln, r1 = n0 + 16 + ln;
  int r0c = (r0 < N) ? r0 : (N - 1);
  int r1c = (r1 < N) ? r1 : (N - 1);
  const float* p0 = pooled + (size_t)r0c * 128 + q * 8;
  const float* p1 = pooled + (size_t)r1c * 128 + q * 8;

  f32x4 acc[2][8];
  #pragma unroll
  for (int mt = 0; mt < 2; ++mt)
    #pragma unroll
    for (int nt = 0; nt < 8; ++nt)
      #pragma unroll
      for (int r = 0; r < 4; ++r) acc[mt][nt][r] = 0.f;

  const bf16x8* Wp = reinterpret_cast<const bf16x8*>(Wopk);
  #pragma unroll
  for (int kt = 0; kt < 4; ++kt) {
    float4 f0a = *reinterpret_cast<const float4*>(p0 + kt * 32);
    float4 f0b = *reinterpret_cast<const float4*>(p0 + kt * 32 + 4);
    float4 f1a = *reinterpret_cast<const float4*>(p1 + kt * 32);
    float4 f1b = *reinterpret_cast<const float4*>(p1 + kt * 32 + 4);
    bf16x8 a0, a1;
    a0[0] = (bf16_t)f0a.x; a0[1] = (bf16_t)f0a.y; a0[2] = (bf16_t)f0a.z; a0[3] = (bf16_t)f0a.w;
    a0[4] = (bf16_t)f0b.x; a0[5] = (bf16_t)f0b.y; a0[6] = (bf16_t)f0b.z; a0[7] = (bf16_t)f0b.w;
    a1[0] = (bf16_t)f1a.x; a1[1] = (bf16_t)f1a.y; a1[2] = (bf16_t)f1a.z; a1[3] = (bf16_t)f1a.w;
    a1[4] = (bf16_t)f1b.x; a1[5] = (bf16_t)f1b.y; a1[6] = (bf16_t)f1b.z; a1[7] = (bf16_t)f1b.w;
    #pragma unroll
    for (int nt = 0; nt < 8; ++nt) {
      bf16x8 bfrag = Wp[(kt * 8 + nt) * 64 + lane];
      acc[0][nt] = __builtin_amdgcn_mfma_f32_16x16x32_bf16(a0, bfrag, acc[0][nt], 0, 0, 0);
      acc[1][nt] = __builtin_amdgcn_mfma_f32_16x16x32_bf16(a1, bfrag, acc[1][nt], 0, 0, 0);
    }
  }

  float bov[8];
  #pragma unroll
  for (int nt = 0; nt < 8; ++nt) bov[nt] = bo[nt * 16 + ln];

  #pragma unroll
  for (int mt = 0; mt < 2; ++mt) {
    #pragma unroll
    for (int r = 0; r < 4; ++r) {
      int row = n0 + mt * 16 + q * 4 + r;
      if (row < N) {
        #pragma unroll
        for (int nt = 0; nt < 8; ++nt) {
          int col = nt * 16 + ln;
          float o = featsIn[(size_t)row * 128 + col] + acc[mt][nt][r] + bov[nt];
          featsOut[(size_t)row * 128 + col] = o;
          featsOutBf[(size_t)row * 128 + col] = (bf16_t)o;
        }
      }
    }
  }
}

// ---------------------------------------------------------------------------
// Block-1 update FUSED with final projection:
// out[n] = (featsIn[n] + pooled[n] @ Wo + bo) . Wf + bf
// ---------------------------------------------------------------------------
__global__ __launch_bounds__(256, 4) void update_final_mfma(
    const float* __restrict__ featsIn, const float* __restrict__ pooled,
    const bf16_t* __restrict__ Wopk, const float* __restrict__ bo,
    const float* __restrict__ Wf, const float* __restrict__ bf_,
    float* __restrict__ out, int N)
{
  const int tid  = threadIdx.x;
  const int lane = tid & 63;
  const int w    = tid >> 6;
  const int q    = lane >> 4;
  const int ln   = lane & 15;
  const int n0   = blockIdx.x * 128 + w * 32;

  int r0 = n0 + ln, r1 = n0 + 16 + ln;
  int r0c = (r0 < N) ? r0 : (N - 1);
  int r1c = (r1 < N) ? r1 : (N - 1);
  const float* p0 = pooled + (size_t)r0c * 128 + q * 8;
  const float* p1 = pooled + (size_t)r1c * 128 + q * 8;

  f32x4 acc[2][8];
  #pragma unroll
  for (int mt = 0; mt < 2; ++mt)
    #pragma unroll
    for (int nt = 0; nt < 8; ++nt)
      #pragma unroll
      for (int r = 0; r < 4; ++r) acc[mt][nt][r] = 0.f;

  const bf16x8* Wp = reinterpret_cast<const bf16x8*>(Wopk);
  #pragma unroll
  for (int kt = 0; kt < 4; ++kt) {
    float4 f0a = *reinterpret_cast<const float4*>(p0 + kt * 32);
    float4 f0b = *reinterpret_cast<const float4*>(p0 + kt * 32 + 4);
    float4 f1a = *reinterpret_cast<const float4*>(p1 + kt * 32);
    float4 f1b = *reinterpret_cast<const float4*>(p1 + kt * 32 + 4);
    bf16x8 a0, a1;
    a0[0] = (bf16_t)f0a.x; a0[1] = (bf16_t)f0a.y; a0[2] = (bf16_t)f0a.z; a0[3] = (bf16_t)f0a.w;
    a0[4] = (bf16_t)f0b.x; a0[5] = (bf16_t)f0b.y; a0[6] = (bf16_t)f0b.z; a0[7] = (bf16_t)f0b.w;
    a1[0] = (bf16_t)f1a.x; a1[1] = (bf16_t)f1a.y; a1[2] = (bf16_t)f1a.z; a1[3] = (bf16_t)f1a.w;
    a1[4] = (bf16_t)f1b.x; a1[5] = (bf16_t)f1b.y; a1[6] = (bf16_t)f1b.z; a1[7] = (bf16_t)f1b.w;
    #pragma unroll
    for (int nt = 0; nt < 8; ++nt) {
      bf16x8 bfrag = Wp[(kt * 8 + nt) * 64 + lane];
      acc[0][nt] = __builtin_amdgcn_mfma_f32_16x16x32_bf16(a0, bfrag, acc[0][nt], 0, 0, 0);
      acc[1][nt] = __builtin_amdgcn_mfma_f32_16x16x32_bf16(a1, bfrag, acc[1][nt], 0, 0, 0);
    }
  }

  float bov[8], wfv[8];
  #pragma unroll
  for (int nt = 0; nt < 8; ++nt) { bov[nt] = bo[nt * 16 + ln]; wfv[nt] = Wf[nt * 16 + ln]; }
  float bfs = bf_[0];

  #pragma unroll
  for (int mt = 0; mt < 2; ++mt) {
    #pragma unroll
    for (int r = 0; r < 4; ++r) {
      int row = n0 + mt * 16 + q * 4 + r;
      float partial = 0.f;
      if (row < N) {
        #pragma unroll
        for (int nt = 0; nt < 8; ++nt) {
          int col = nt * 16 + ln;
          float o = featsIn[(size_t)row * 128 + col] + acc[mt][nt][r] + bov[nt];
          partial += o * wfv[nt];
        }
      }
      partial += __shfl_xor(partial, 1);
      partial += __shfl_xor(partial, 2);
      partial += __shfl_xor(partial, 4);
      partial += __shfl_xor(partial, 8);
      if (ln == 0 && row < N) out[row] = partial + bfs;
    }
  }
}

// ---------------------------------------------------------------------------
extern "C" void kernel_launch(void* const* d_in, const int* in_sizes, int n_in,
                              void* d_out, int out_size, void* d_ws, size_t ws_size,
                              hipStream_t stream)
{
  const float* interpolated = (const float*)d_in[0];
  const float* add_info     = (const float*)d_in[1];
  const int*   nbr          = (const int*)d_in[2];
  const int*   segs         = (const int*)d_in[3];
  const float* Wb0 = (const float*)d_in[4];
  const float* bb0 = (const float*)d_in[5];
  const float* Wo0 = (const float*)d_in[6];
  const float* bo0 = (const float*)d_in[7];
  const float* Wb1 = (const float*)d_in[8];
  const float* bb1 = (const float*)d_in[9];
  const float* Wo1 = (const float*)d_in[10];
  const float* bo1 = (const float*)d_in[11];
  const float* Wf  = (const float*)d_in[12];
  const float* bf_ = (const float*)d_in[13];

  const int N = in_sizes[0] / 128;
  const int E = in_sizes[2];
  float* out = (float*)d_out;

  // workspace layout
  float* pooled = (float*)d_ws;                              // N*128 f32
  float* featsB = pooled + (size_t)N * 128;                  // N*128 f32
  bf16_t* featsB_bf = (bf16_t*)(featsB + (size_t)N * 128);   // N*128 bf16
  bf16_t* Ybf       = featsB_bf + (size_t)N * 128;           // N*128 bf16
  bf16_t* Wtpk0 = Ybf + (size_t)N * 128;                     // 16384
  bf16_t* Wtpk1 = Wtpk0 + 16384;
  bf16_t* Wopk0 = Wtpk1 + 16384;
  bf16_t* Wopk1 = Wopk0 + 16384;

  const int ugrid = (N + 127) / 128;
  const int egrid = (E + CH * 4 - 1) / (CH * 4);

  // single pack launch for all four 128x128 weights (Wb top rows 0..127, Wo)
  PackArgs pa;
  pa.W[0] = Wb0; pa.P[0] = Wtpk0;
  pa.W[1] = Wb1; pa.P[1] = Wtpk1;
  pa.W[2] = Wo0; pa.P[2] = Wopk0;
  pa.W[3] = Wo1; pa.P[3] = Wopk1;
  pack4_kernel<<<256, 256, 0, stream>>>(pa);

  // block 0 (yproj reads fp32 directly -> no convert pass, no Xbf buffer)
  yproj_f32<<<ugrid, 256, 0, stream>>>(interpolated, Wtpk0, Ybf, pooled, N);
  edge_stream<<<egrid, 256, 0, stream>>>(Ybf, Wb0, bb0, add_info, nbr, segs,
                                         pooled, E);
  update_mfma<<<ugrid, 256, 0, stream>>>(interpolated, pooled, Wopk0, bo0,
                                         featsB, featsB_bf, N);

  // block 1
  yproj_bf16<<<ugrid, 256, 0, stream>>>(featsB_bf, Wtpk1, Ybf, pooled, N);
  edge_stream<<<egrid, 256, 0, stream>>>(Ybf, Wb1, bb1, add_info, nbr, segs,
                                         pooled, E);
  update_final_mfma<<<ugrid, 256, 0, stream>>>(featsB, pooled, Wopk1, bo1,
                                               Wf, bf_, out, N);
}

// Round 11
// 306.827 us; speedup vs baseline: 1.6443x; 1.0039x over previous
//
#include <hip/hip_runtime.h>
#include <limits.h>
#include <cstdint>

typedef __bf16 bf16_t;
typedef __attribute__((ext_vector_type(8))) __bf16 bf16x8;
typedef __attribute__((ext_vector_type(4))) float f32x4;
typedef __attribute__((ext_vector_type(2))) float f32x2;

#define CH 64     // edges per wave in edge_stream

__device__ __forceinline__ float rlf(float v, int l) {
  return __int_as_float(__builtin_amdgcn_readlane(__float_as_int(v), l));
}

// ---------------------------------------------------------------------------
// Pack all four 128x128 weight matrices -> MFMA B-frag order, one launch.
// packed[((kt*8+nt)*64+L)*8+j] = W[kt*32+(L>>4)*8+j][nt*16+(L&15)]
// ---------------------------------------------------------------------------
struct PackArgs {
  const float* W[4];
  bf16_t* P[4];
};

__global__ __launch_bounds__(256) void pack4_kernel(PackArgs args) {
  int idx = blockIdx.x * blockDim.x + threadIdx.x;   // 4 * 16384
  int which = idx >> 14;
  int r = idx & 16383;
  int j  = r & 7;
  int L  = (r >> 3) & 63;
  int nt = (r >> 9) & 7;
  int kt = r >> 12;
  int k = kt * 32 + (L >> 4) * 8 + j;
  int n = nt * 16 + (L & 15);
  args.P[which][r] = (bf16_t)args.W[which][(size_t)k * 128 + n];
}

// ---------------------------------------------------------------------------
// Y = X @ Wtop via bf16 MFMA. X is fp32 (converted in-register). Also zeroes
// pooled rows for this WG (fuses zero_kernel).
// ---------------------------------------------------------------------------
__global__ __launch_bounds__(256, 4) void yproj_f32(
    const float* __restrict__ X, const bf16_t* __restrict__ Wtpk,
    bf16_t* __restrict__ Ybf, float* __restrict__ pooled, int N)
{
  const int tid = threadIdx.x;
  const int base = blockIdx.x * 128;

  float4 z = make_float4(0.f, 0.f, 0.f, 0.f);
  #pragma unroll
  for (int i = 0; i < 16; ++i) {
    int idx = tid + i * 256;
    int row = base + (idx >> 5);
    if (row < N)
      reinterpret_cast<float4*>(pooled)[(size_t)row * 32 + (idx & 31)] = z;
  }

  const int lane = tid & 63;
  const int w    = tid >> 6;
  const int q    = lane >> 4;
  const int ln   = lane & 15;
  const int n0   = base + w * 32;

  int r0 = n0 + ln, r1 = n0 + 16 + ln;
  int r0c = (r0 < N) ? r0 : (N - 1);
  int r1c = (r1 < N) ? r1 : (N - 1);
  const float* x0 = X + (size_t)r0c * 128 + q * 8;
  const float* x1 = X + (size_t)r1c * 128 + q * 8;

  f32x4 acc[2][8];
  #pragma unroll
  for (int mt = 0; mt < 2; ++mt)
    #pragma unroll
    for (int nt = 0; nt < 8; ++nt)
      #pragma unroll
      for (int r = 0; r < 4; ++r) acc[mt][nt][r] = 0.f;

  const bf16x8* Wp = reinterpret_cast<const bf16x8*>(Wtpk);
  #pragma unroll
  for (int kt = 0; kt < 4; ++kt) {
    float4 f0a = *reinterpret_cast<const float4*>(x0 + kt * 32);
    float4 f0b = *reinterpret_cast<const float4*>(x0 + kt * 32 + 4);
    float4 f1a = *reinterpret_cast<const float4*>(x1 + kt * 32);
    float4 f1b = *reinterpret_cast<const float4*>(x1 + kt * 32 + 4);
    bf16x8 a0, a1;
    a0[0] = (bf16_t)f0a.x; a0[1] = (bf16_t)f0a.y; a0[2] = (bf16_t)f0a.z; a0[3] = (bf16_t)f0a.w;
    a0[4] = (bf16_t)f0b.x; a0[5] = (bf16_t)f0b.y; a0[6] = (bf16_t)f0b.z; a0[7] = (bf16_t)f0b.w;
    a1[0] = (bf16_t)f1a.x; a1[1] = (bf16_t)f1a.y; a1[2] = (bf16_t)f1a.z; a1[3] = (bf16_t)f1a.w;
    a1[4] = (bf16_t)f1b.x; a1[5] = (bf16_t)f1b.y; a1[6] = (bf16_t)f1b.z; a1[7] = (bf16_t)f1b.w;
    #pragma unroll
    for (int nt = 0; nt < 8; ++nt) {
      bf16x8 bfrag = Wp[(kt * 8 + nt) * 64 + lane];
      acc[0][nt] = __builtin_amdgcn_mfma_f32_16x16x32_bf16(a0, bfrag, acc[0][nt], 0, 0, 0);
      acc[1][nt] = __builtin_amdgcn_mfma_f32_16x16x32_bf16(a1, bfrag, acc[1][nt], 0, 0, 0);
    }
  }

  #pragma unroll
  for (int mt = 0; mt < 2; ++mt) {
    #pragma unroll
    for (int r = 0; r < 4; ++r) {
      int row = n0 + mt * 16 + q * 4 + r;
      if (row < N) {
        #pragma unroll
        for (int nt = 0; nt < 8; ++nt) {
          int col = nt * 16 + ln;
          Ybf[(size_t)row * 128 + col] = (bf16_t)acc[mt][nt][r];
        }
      }
    }
  }
}

// ---------------------------------------------------------------------------
// Same but X already bf16 (block 1: reads featsB_bf written by update_mfma).
// ---------------------------------------------------------------------------
__global__ __launch_bounds__(256, 4) void yproj_bf16(
    const bf16_t* __restrict__ Xbf, const bf16_t* __restrict__ Wtpk,
    bf16_t* __restrict__ Ybf, float* __restrict__ pooled, int N)
{
  const int tid = threadIdx.x;
  const int base = blockIdx.x * 128;

  float4 z = make_float4(0.f, 0.f, 0.f, 0.f);
  #pragma unroll
  for (int i = 0; i < 16; ++i) {
    int idx = tid + i * 256;
    int row = base + (idx >> 5);
    if (row < N)
      reinterpret_cast<float4*>(pooled)[(size_t)row * 32 + (idx & 31)] = z;
  }

  const int lane = tid & 63;
  const int w    = tid >> 6;
  const int q    = lane >> 4;
  const int ln   = lane & 15;
  const int n0   = base + w * 32;

  int r0 = n0 + ln, r1 = n0 + 16 + ln;
  int r0c = (r0 < N) ? r0 : (N - 1);
  int r1c = (r1 < N) ? r1 : (N - 1);
  const bf16_t* x0 = Xbf + (size_t)r0c * 128 + q * 8;
  const bf16_t* x1 = Xbf + (size_t)r1c * 128 + q * 8;

  f32x4 acc[2][8];
  #pragma unroll
  for (int mt = 0; mt < 2; ++mt)
    #pragma unroll
    for (int nt = 0; nt < 8; ++nt)
      #pragma unroll
      for (int r = 0; r < 4; ++r) acc[mt][nt][r] = 0.f;

  const bf16x8* Wp = reinterpret_cast<const bf16x8*>(Wtpk);
  #pragma unroll
  for (int kt = 0; kt < 4; ++kt) {
    bf16x8 a0 = *reinterpret_cast<const bf16x8*>(x0 + kt * 32);
    bf16x8 a1 = *reinterpret_cast<const bf16x8*>(x1 + kt * 32);
    #pragma unroll
    for (int nt = 0; nt < 8; ++nt) {
      bf16x8 bfrag = Wp[(kt * 8 + nt) * 64 + lane];
      acc[0][nt] = __builtin_amdgcn_mfma_f32_16x16x32_bf16(a0, bfrag, acc[0][nt], 0, 0, 0);
      acc[1][nt] = __builtin_amdgcn_mfma_f32_16x16x32_bf16(a1, bfrag, acc[1][nt], 0, 0, 0);
    }
  }

  #pragma unroll
  for (int mt = 0; mt < 2; ++mt) {
    #pragma unroll
    for (int r = 0; r < 4; ++r) {
      int row = n0 + mt * 16 + q * 4 + r;
      if (row < N) {
        #pragma unroll
        for (int nt = 0; nt < 8; ++nt) {
          int col = nt * 16 + ln;
          Ybf[(size_t)row * 128 + col] = (bf16_t)acc[mt][nt][r];
        }
      }
    }
  }
}

// ---------------------------------------------------------------------------
// Edge pass. Chunk-header vector loads + readlane broadcast (zero SMEM in hot
// loop), packed fp32 math, and a 4-buffer rotating pipeline: loads for group
// g+3 are issued BEFORE computing group g -> 24 outstanding gathers per wave,
// issue-to-use distance ~3 groups (covers loaded L3/fabric latency).
// ---------------------------------------------------------------------------
__global__ __launch_bounds__(256) void edge_stream(
    const bf16_t* __restrict__ Y,        // N x 128 bf16
    const float* __restrict__ Wb,        // 132 x 128; rows 128..131 = Wbot
    const float* __restrict__ bb,        // 128
    const float* __restrict__ add_info,  // E x 4
    const int* __restrict__ nbr, const int* __restrict__ segs,
    float* __restrict__ pooled, int E)
{
  const int lane = threadIdx.x & 63;
  const int wv = __builtin_amdgcn_readfirstlane(threadIdx.x >> 6);  // SGPR
  const int e0 = (blockIdx.x * 4 + wv) * CH;                        // uniform
  if (e0 >= E) return;
  const int c0 = lane * 2;

  f32x2 wk[4];
  #pragma unroll
  for (int k = 0; k < 4; ++k) {
    wk[k].x = Wb[(size_t)(128 + k) * 128 + c0];
    wk[k].y = Wb[(size_t)(128 + k) * 128 + c0 + 1];
  }
  f32x2 bbv;
  bbv.x = bb[c0]; bbv.y = bb[c0 + 1];

  unsigned* pooled_u = reinterpret_cast<unsigned*>(pooled);
  f32x2 v; v.x = 0.f; v.y = 0.f;

  if (e0 + CH <= E) {
    // ---- chunk header: cooperative vector loads ----
    int v_nbr = nbr[e0 + lane];
    int v_sg  = segs[e0 + lane];
    float v_ai[4];
    #pragma unroll
    for (int r = 0; r < 4; ++r)
      v_ai[r] = add_info[(size_t)e0 * 4 + r * 64 + lane];

    int cur = __builtin_amdgcn_readlane(v_sg, 0);

    // ---- 4-buffer rotating pipeline, prefetch 3 groups ahead ----
    unsigned ybuf[4][8];
    #pragma unroll
    for (int p = 0; p < 3; ++p) {
      #pragma unroll
      for (int j = 0; j < 8; ++j) {
        int rn = __builtin_amdgcn_readlane(v_nbr, p * 8 + j);
        ybuf[p][j] = *((const unsigned*)(Y + (size_t)rn * 128) + lane);
      }
    }

    #pragma unroll
    for (int g = 0; g < CH / 8; ++g) {
      // issue group g+3 first (into buffer (g+3)&3 != g&3)
      if (g + 3 < CH / 8) {
        #pragma unroll
        for (int j = 0; j < 8; ++j) {
          int rn = __builtin_amdgcn_readlane(v_nbr, (g + 3) * 8 + j);
          ybuf[(g + 3) & 3][j] = *((const unsigned*)(Y + (size_t)rn * 128) + lane);
        }
      }
      // compute group g
      #pragma unroll
      for (int j = 0; j < 8; ++j) {
        const int i = g * 8 + j;                              // constant
        int sg = __builtin_amdgcn_readlane(v_sg, i);
        if (sg != cur) {                                      // uniform branch
          if (v.x > 0.f) atomicMax(&pooled_u[(size_t)cur * 128 + c0], __float_as_uint(v.x));
          if (v.y > 0.f) atomicMax(&pooled_u[(size_t)cur * 128 + c0 + 1], __float_as_uint(v.y));
          v.x = 0.f; v.y = 0.f; cur = sg;
        }
        unsigned yb = ybuf[g & 3][j];
        f32x2 y;
        y.x = __uint_as_float(yb << 16);
        y.y = __uint_as_float(yb & 0xffff0000u);
        float a0 = rlf(v_ai[i >> 4], (i * 4 + 0) & 63);
        float a1 = rlf(v_ai[i >> 4], (i * 4 + 1) & 63);
        float a2 = rlf(v_ai[i >> 4], (i * 4 + 2) & 63);
        float a3 = rlf(v_ai[i >> 4], (i * 4 + 3) & 63);
        f32x2 t = bbv + a0 * wk[0];      // v_pk_fma_f32 chain
        t += a1 * wk[1];
        t += a2 * wk[2];
        t += a3 * wk[3];
        t += y;                           // v_pk_add_f32
        v = __builtin_elementwise_max(v, t);   // v_pk_max_f32
      }
    }
    if (v.x > 0.f) atomicMax(&pooled_u[(size_t)cur * 128 + c0], __float_as_uint(v.x));
    if (v.y > 0.f) atomicMax(&pooled_u[(size_t)cur * 128 + c0 + 1], __float_as_uint(v.y));
  } else {
    // ---- tail path ----
    int cur = segs[e0];
    const int rem = E - e0;
    for (int i = 0; i < rem; ++i) {
      const int e = e0 + i;
      int sg = segs[e];
      if (sg != cur) {
        if (v.x > 0.f) atomicMax(&pooled_u[(size_t)cur * 128 + c0], __float_as_uint(v.x));
        if (v.y > 0.f) atomicMax(&pooled_u[(size_t)cur * 128 + c0 + 1], __float_as_uint(v.y));
        v.x = 0.f; v.y = 0.f; cur = sg;
      }
      unsigned yb = *reinterpret_cast<const unsigned*>(Y + (size_t)nbr[e] * 128 + c0);
      float y0 = __uint_as_float(yb << 16);
      float y1 = __uint_as_float(yb & 0xffff0000u);
      const float* ai = add_info + (size_t)e * 4;
      float a0 = ai[0], a1 = ai[1], a2 = ai[2], a3 = ai[3];
      float t0 = y0 + bbv.x + a0 * wk[0].x + a1 * wk[1].x + a2 * wk[2].x + a3 * wk[3].x;
      float t1 = y1 + bbv.y + a0 * wk[0].y + a1 * wk[1].y + a2 * wk[2].y + a3 * wk[3].y;
      v.x = fmaxf(v.x, t0);
      v.y = fmaxf(v.y, t1);
    }
    if (v.x > 0.f) atomicMax(&pooled_u[(size_t)cur * 128 + c0], __float_as_uint(v.x));
    if (v.y > 0.f) atomicMax(&pooled_u[(size_t)cur * 128 + c0 + 1], __float_as_uint(v.y));
  }
}

// ---------------------------------------------------------------------------
// featsOut = featsIn + pooled @ Wo + bo via bf16 MFMA; emits bf16 copy.
// ---------------------------------------------------------------------------
__global__ __launch_bounds__(256, 4) void update_mfma(
    const float* __restrict__ featsIn, const float* __restrict__ pooled,
    const bf16_t* __restrict__ Wopk, const float* __restrict__ bo,
    float* __restrict__ featsOut, bf16_t* __restrict__ featsOutBf, int N)
{
  const int tid  = threadIdx.x;
  const int lane = tid & 63;
  const int w    = tid >> 6;
  const int q    = lane >> 4;
  const int ln   = lane & 15;
  const int n0   = blockIdx.x * 128 + w * 32;

  int r0 = n0 + ln, r1 = n0 + 16 + ln;
  int r0c = (r0 < N) ? r0 : (N - 1);
  int r1c = (r1 < N) ? r1 : (N - 1);
  const float* p0 = pooled + (size_t)r0c * 128 + q * 8;
  const float* p1 = pooled + (size_t)r1c * 128 + q * 8;

  f32x4 acc[2][8];
  #pragma unroll
  for (int mt = 0; mt < 2; ++mt)
    #pragma unroll
    for (int nt = 0; nt < 8; ++nt)
      #pragma unroll
      for (int r = 0; r < 4; ++r) acc[mt][nt][r] = 0.f;

  const bf16x8* Wp = reinterpret_cast<const bf16x8*>(Wopk);
  #pragma unroll
  for (int kt = 0; kt < 4; ++kt) {
    float4 f0a = *reinterpret_cast<const float4*>(p0 + kt * 32);
    float4 f0b = *reinterpret_cast<const float4*>(p0 + kt * 32 + 4);
    float4 f1a = *reinterpret_cast<const float4*>(p1 + kt * 32);
    float4 f1b = *reinterpret_cast<const float4*>(p1 + kt * 32 + 4);
    bf16x8 a0, a1;
    a0[0] = (bf16_t)f0a.x; a0[1] = (bf16_t)f0a.y; a0[2] = (bf16_t)f0a.z; a0[3] = (bf16_t)f0a.w;
    a0[4] = (bf16_t)f0b.x; a0[5] = (bf16_t)f0b.y; a0[6] = (bf16_t)f0b.z; a0[7] = (bf16_t)f0b.w;
    a1[0] = (bf16_t)f1a.x; a1[1] = (bf16_t)f1a.y; a1[2] = (bf16_t)f1a.z; a1[3] = (bf16_t)f1a.w;
    a1[4] = (bf16_t)f1b.x; a1[5] = (bf16_t)f1b.y; a1[6] = (bf16_t)f1b.z; a1[7] = (bf16_t)f1b.w;
    #pragma unroll
    for (int nt = 0; nt < 8; ++nt) {
      bf16x8 bfrag = Wp[(kt * 8 + nt) * 64 + lane];
      acc[0][nt] = __builtin_amdgcn_mfma_f32_16x16x32_bf16(a0, bfrag, acc[0][nt], 0, 0, 0);
      acc[1][nt] = __builtin_amdgcn_mfma_f32_16x16x32_bf16(a1, bfrag, acc[1][nt], 0, 0, 0);
    }
  }

  float bov[8];
  #pragma unroll
  for (int nt = 0; nt < 8; ++nt) bov[nt] = bo[nt * 16 + ln];

  #pragma unroll
  for (int mt = 0; mt < 2; ++mt) {
    #pragma unroll
    for (int r = 0; r < 4; ++r) {
      int row = n0 + mt * 16 + q * 4 + r;
      if (row < N) {
        #pragma unroll
        for (int nt = 0; nt < 8; ++nt) {
          int col = nt * 16 + ln;
          float o = featsIn[(size_t)row * 128 + col] + acc[mt][nt][r] + bov[nt];
          featsOut[(size_t)row * 128 + col] = o;
          featsOutBf[(size_t)row * 128 + col] = (bf16_t)o;
        }
      }
    }
  }
}

// ---------------------------------------------------------------------------
// Block-1 update FUSED with final projection:
// out[n] = (featsIn[n] + pooled[n] @ Wo + bo) . Wf + bf
// ---------------------------------------------------------------------------
__global__ __launch_bounds__(256, 4) void update_final_mfma(
    const float* __restrict__ featsIn, const float* __restrict__ pooled,
    const bf16_t* __restrict__ Wopk, const float* __restrict__ bo,
    const float* __restrict__ Wf, const float* __restrict__ bf_,
    float* __restrict__ out, int N)
{
  const int tid  = threadIdx.x;
  const int lane = tid & 63;
  const int w    = tid >> 6;
  const int q    = lane >> 4;
  const int ln   = lane & 15;
  const int n0   = blockIdx.x * 128 + w * 32;

  int r0 = n0 + ln, r1 = n0 + 16 + ln;
  int r0c = (r0 < N) ? r0 : (N - 1);
  int r1c = (r1 < N) ? r1 : (N - 1);
  const float* p0 = pooled + (size_t)r0c * 128 + q * 8;
  const float* p1 = pooled + (size_t)r1c * 128 + q * 8;

  f32x4 acc[2][8];
  #pragma unroll
  for (int mt = 0; mt < 2; ++mt)
    #pragma unroll
    for (int nt = 0; nt < 8; ++nt)
      #pragma unroll
      for (int r = 0; r < 4; ++r) acc[mt][nt][r] = 0.f;

  const bf16x8* Wp = reinterpret_cast<const bf16x8*>(Wopk);
  #pragma unroll
  for (int kt = 0; kt < 4; ++kt) {
    float4 f0a = *reinterpret_cast<const float4*>(p0 + kt * 32);
    float4 f0b = *reinterpret_cast<const float4*>(p0 + kt * 32 + 4);
    float4 f1a = *reinterpret_cast<const float4*>(p1 + kt * 32);
    float4 f1b = *reinterpret_cast<const float4*>(p1 + kt * 32 + 4);
    bf16x8 a0, a1;
    a0[0] = (bf16_t)f0a.x; a0[1] = (bf16_t)f0a.y; a0[2] = (bf16_t)f0a.z; a0[3] = (bf16_t)f0a.w;
    a0[4] = (bf16_t)f0b.x; a0[5] = (bf16_t)f0b.y; a0[6] = (bf16_t)f0b.z; a0[7] = (bf16_t)f0b.w;
    a1[0] = (bf16_t)f1a.x; a1[1] = (bf16_t)f1a.y; a1[2] = (bf16_t)f1a.z; a1[3] = (bf16_t)f1a.w;
    a1[4] = (bf16_t)f1b.x; a1[5] = (bf16_t)f1b.y; a1[6] = (bf16_t)f1b.z; a1[7] = (bf16_t)f1b.w;
    #pragma unroll
    for (int nt = 0; nt < 8; ++nt) {
      bf16x8 bfrag = Wp[(kt * 8 + nt) * 64 + lane];
      acc[0][nt] = __builtin_amdgcn_mfma_f32_16x16x32_bf16(a0, bfrag, acc[0][nt], 0, 0, 0);
      acc[1][nt] = __builtin_amdgcn_mfma_f32_16x16x32_bf16(a1, bfrag, acc[1][nt], 0, 0, 0);
    }
  }

  float bov[8], wfv[8];
  #pragma unroll
  for (int nt = 0; nt < 8; ++nt) { bov[nt] = bo[nt * 16 + ln]; wfv[nt] = Wf[nt * 16 + ln]; }
  float bfs = bf_[0];

  #pragma unroll
  for (int mt = 0; mt < 2; ++mt) {
    #pragma unroll
    for (int r = 0; r < 4; ++r) {
      int row = n0 + mt * 16 + q * 4 + r;
      float partial = 0.f;
      if (row < N) {
        #pragma unroll
        for (int nt = 0; nt < 8; ++nt) {
          int col = nt * 16 + ln;
          float o = featsIn[(size_t)row * 128 + col] + acc[mt][nt][r] + bov[nt];
          partial += o * wfv[nt];
        }
      }
      partial += __shfl_xor(partial, 1);
      partial += __shfl_xor(partial, 2);
      partial += __shfl_xor(partial, 4);
      partial += __shfl_xor(partial, 8);
      if (ln == 0 && row < N) out[row] = partial + bfs;
    }
  }
}

// ---------------------------------------------------------------------------
extern "C" void kernel_launch(void* const* d_in, const int* in_sizes, int n_in,
                              void* d_out, int out_size, void* d_ws, size_t ws_size,
                              hipStream_t stream)
{
  const float* interpolated = (const float*)d_in[0];
  const float* add_info     = (const float*)d_in[1];
  const int*   nbr          = (const int*)d_in[2];
  const int*   segs         = (const int*)d_in[3];
  const float* Wb0 = (const float*)d_in[4];
  const float* bb0 = (const float*)d_in[5];
  const float* Wo0 = (const float*)d_in[6];
  const float* bo0 = (const float*)d_in[7];
  const float* Wb1 = (const float*)d_in[8];
  const float* bb1 = (const float*)d_in[9];
  const float* Wo1 = (const float*)d_in[10];
  const float* bo1 = (const float*)d_in[11];
  const float* Wf  = (const float*)d_in[12];
  const float* bf_ = (const float*)d_in[13];

  const int N = in_sizes[0] / 128;
  const int E = in_sizes[2];
  float* out = (float*)d_out;

  // workspace layout
  float* pooled = (float*)d_ws;                              // N*128 f32
  float* featsB = pooled + (size_t)N * 128;                  // N*128 f32
  bf16_t* featsB_bf = (bf16_t*)(featsB + (size_t)N * 128);   // N*128 bf16
  bf16_t* Ybf       = featsB_bf + (size_t)N * 128;           // N*128 bf16
  bf16_t* Wtpk0 = Ybf + (size_t)N * 128;                     // 16384
  bf16_t* Wtpk1 = Wtpk0 + 16384;
  bf16_t* Wopk0 = Wtpk1 + 16384;
  bf16_t* Wopk1 = Wopk0 + 16384;

  const int ugrid = (N + 127) / 128;
  const int egrid = (E + CH * 4 - 1) / (CH * 4);

  // single pack launch for all four 128x128 weights (Wb top rows 0..127, Wo)
  PackArgs pa;
  pa.W[0] = Wb0; pa.P[0] = Wtpk0;
  pa.W[1] = Wb1; pa.P[1] = Wtpk1;
  pa.W[2] = Wo0; pa.P[2] = Wopk0;
  pa.W[3] = Wo1; pa.P[3] = Wopk1;
  pack4_kernel<<<256, 256, 0, stream>>>(pa);

  // block 0 (yproj reads fp32 directly -> no convert pass, no Xbf buffer)
  yproj_f32<<<ugrid, 256, 0, stream>>>(interpolated, Wtpk0, Ybf, pooled, N);
  edge_stream<<<egrid, 256, 0, stream>>>(Ybf, Wb0, bb0, add_info, nbr, segs,
                                         pooled, E);
  update_mfma<<<ugrid, 256, 0, stream>>>(interpolated, pooled, Wopk0, bo0,
                                         featsB, featsB_bf, N);

  // block 1
  yproj_bf16<<<ugrid, 256, 0, stream>>>(featsB_bf, Wtpk1, Ybf, pooled, N);
  edge_stream<<<egrid, 256, 0, stream>>>(Ybf, Wb1, bb1, add_info, nbr, segs,
                                         pooled, E);
  update_final_mfma<<<ugrid, 256, 0, stream>>>(featsB, pooled, Wopk1, bo1,
                                               Wf, bf_, out, N);
}